// Round 3
// baseline (184.321 us; speedup 1.0000x reference)
//
#include <hip/hip_runtime.h>
#include <hip/hip_fp16.h>

#define D_ 160
#define H_ 192
#define W_ 160
#define PLANE (H_*W_)          // 30720
#define VOL (D_*PLANE)         // 4915200 per sample
#define NS 2
#define WSZ 729.0f

// A/B arrays: 5 quantities (I, J, I*I, J*J, I*J), each VOL fp16, layout [q][d][h][w]

// ---------------- zero accumulators ----------------
__global__ void k_zero(float* acc) {
    if (threadIdx.x < NS) acc[threadIdx.x] = 0.f;
}

// ---------------- pass 1: products + W-axis 9-box-sum -> fp16 A ----------------
__global__ __launch_bounds__(256) void k_w(const float* __restrict__ I,
                                           const float* __restrict__ J,
                                           __half* __restrict__ A,
                                           int s0, long Astride) {
    int b  = blockIdx.x;
    int sl = b / 2400;
    int t  = (b % 2400) * 256 + threadIdx.x;
    int s  = s0 + sl;
    int seg = t % 20;
    int r   = t / 20;                       // d*H_ + h, 0..30719
    long gbase = ((long)s * 30720 + r) * W_;
    long lbase = (long)r * W_;
    int w0 = seg * 8;
    __half* As = A + sl * Astride;

    float vI[16], vJ[16];
#pragma unroll
    for (int bq = 0; bq < 4; ++bq) {
        int f0 = w0 - 4 + 4 * bq;           // multiple of 4 -> 16B aligned
        if (f0 >= 0 && f0 <= W_ - 4) {
            float4 a = *reinterpret_cast<const float4*>(I + gbase + f0);
            float4 c = *reinterpret_cast<const float4*>(J + gbase + f0);
            vI[4*bq+0]=a.x; vI[4*bq+1]=a.y; vI[4*bq+2]=a.z; vI[4*bq+3]=a.w;
            vJ[4*bq+0]=c.x; vJ[4*bq+1]=c.y; vJ[4*bq+2]=c.z; vJ[4*bq+3]=c.w;
        } else {
#pragma unroll
            for (int k = 0; k < 4; ++k) { vI[4*bq+k] = 0.f; vJ[4*bq+k] = 0.f; }
        }
    }

#pragma unroll
    for (int q = 0; q < 5; ++q) {
        float p[16];
#pragma unroll
        for (int i = 0; i < 16; ++i) {
            float a = vI[i], bb = vJ[i];
            p[i] = (q == 0) ? a : (q == 1) ? bb : (q == 2) ? a*a : (q == 3) ? bb*bb : a*bb;
        }
        float o[8];
        float ssum = 0.f;
#pragma unroll
        for (int i = 0; i < 9; ++i) ssum += p[i];
        o[0] = ssum;
#pragma unroll
        for (int k = 1; k < 8; ++k) { ssum += p[k + 8] - p[k - 1]; o[k] = ssum; }

        union U { __half h[8]; int4 v; } u;
#pragma unroll
        for (int k = 0; k < 8; ++k) u.h[k] = __float2half(o[k]);
        __half* outp = As + (long)q * VOL + lbase + w0;
        *reinterpret_cast<int4*>(outp) = u.v;   // 16B store
    }
}

// ---------------- pass 2: H-axis 9-box-sum, fp16 A -> fp16 B ----------------
__global__ __launch_bounds__(256) void k_h(const __half* __restrict__ P, long stride) {
    int b  = blockIdx.x;
    int sl = b / 1000;
    int t  = (b % 1000) * 256 + threadIdx.x;    // 0..255999
    int wp    = t % 80;
    int chunk = (t / 80) % 4;
    int d     = (t / 320) % 160;
    int q     = t / 51200;
    int h0 = chunk * 48;
    long base = (long)q * VOL + (long)d * PLANE + 2 * wp;
    const __half* Ab = P + (long)sl * stride + base;
    __half*       Bb = const_cast<__half*>(P) + (long)sl * stride + 5L * VOL + base;

    float2 ring[9];
#pragma unroll
    for (int i = 0; i < 9; ++i) ring[i] = make_float2(0.f, 0.f);
    float sx = 0.f, sy = 0.f;

    for (int i = 0; i < 56; ++i) {
        int h_in = h0 - 4 + i;
        float2 v = make_float2(0.f, 0.f);
        if (h_in >= 0 && h_in < H_) {
            __half2 hv = *reinterpret_cast<const __half2*>(Ab + (long)h_in * W_);
            v = __half22float2(hv);
        }
        sx += v.x - ring[0].x;
        sy += v.y - ring[0].y;
#pragma unroll
        for (int k = 0; k < 8; ++k) ring[k] = ring[k + 1];
        ring[8] = v;
        if (i >= 8) {
            int h_out = h_in - 4;
            *reinterpret_cast<__half2*>(Bb + (long)h_out * W_) = __floats2half2_rn(sx, sy);
        }
    }
}

// ---------------- pass 3: D-axis 9-box-sum + cc + reduction ----------------
// one thread per (h,w) column x 8 d-chunks of 20; FULLY UNROLLED so the
// 5x9 window ring lives in renamed registers (no movs, no re-loads)
// threads/sample = 30720*8 = 245760 -> 960 blocks
__global__ __launch_bounds__(256) void k_d(const __half* __restrict__ B,
                                           float* __restrict__ acc, int s0, long stride) {
    int sl = blockIdx.x / 960;
    int t  = (blockIdx.x % 960) * 256 + threadIdx.x;   // 0..245759
    const __half* Bs = B + (long)sl * stride;
    int col   = t % 30720;                        // h*W_ + w
    int chunk = t / 30720;                        // 0..7
    int d0 = chunk * 20;
    const __half* base = Bs + col;                // + q*VOL + d*PLANE

    float win[5][9], sum[5];
#pragma unroll
    for (int q = 0; q < 5; ++q) {
        sum[q] = 0.f;
#pragma unroll
        for (int i = 0; i < 9; ++i) {
            int d = d0 + i - 4;
            float v = (d >= 0) ? __half2float(base[(long)q * VOL + (long)d * PLANE]) : 0.f;
            win[q][i] = v; sum[q] += v;
        }
    }

    float local = 0.f;
#pragma unroll
    for (int dd = 0; dd < 20; ++dd) {
        float Is = sum[0], Js = sum[1], I2 = sum[2], J2 = sum[3], IJ = sum[4];
        float uI = Is * (1.f / WSZ), uJ = Js * (1.f / WSZ);
        float cross = IJ - uJ * Is - uI * Js + uI * uJ * WSZ;
        float Iv = I2 - 2.f * uI * Is + uI * uI * WSZ;
        float Jv = J2 - 2.f * uJ * Js + uJ * uJ * WSZ;
        float cc = 1.f - cross * cross / (Iv * Jv + 1e-5f);
        local += cc;

        int dn = d0 + dd + 5;
#pragma unroll
        for (int q = 0; q < 5; ++q) {
            float nv = (dn < D_) ? __half2float(base[(long)q * VOL + (long)dn * PLANE]) : 0.f;
            sum[q] += nv - win[q][0];
#pragma unroll
            for (int i = 0; i < 8; ++i) win[q][i] = win[q][i + 1];
            win[q][8] = nv;
        }
    }

    __shared__ float red[256];
    red[threadIdx.x] = local;
    __syncthreads();
    for (int off = 128; off > 0; off >>= 1) {
        if (threadIdx.x < off) red[threadIdx.x] += red[threadIdx.x + off];
        __syncthreads();
    }
    if (threadIdx.x == 0) atomicAdd(acc + s0 + sl, red[0]);
}

// ---------------- finalize ----------------
__global__ void k_fin(const float* __restrict__ acc, float* __restrict__ out) {
    if (threadIdx.x < NS) out[threadIdx.x] = acc[threadIdx.x] * (1.f / (float)VOL);
}

extern "C" void kernel_launch(void* const* d_in, const int* in_sizes, int n_in,
                              void* d_out, int out_size, void* d_ws, size_t ws_size,
                              hipStream_t stream) {
    const float* J = (const float*)d_in[0];   // y_pred
    const float* I = (const float*)d_in[1];   // y_true
    float* out = (float*)d_out;
    __half* W  = (__half*)d_ws;

    const long SAMP = 10L * VOL;              // elements (A + B) per sample, fp16
    size_t bat_need = (size_t)(2 * SAMP) * sizeof(__half) + 8;

    if (ws_size >= bat_need) {
        // layout: [A0 B0 | A1 B1 | acc]
        float* acc = (float*)((char*)d_ws + (size_t)(2 * SAMP) * sizeof(__half));
        k_zero<<<1, 64, 0, stream>>>(acc);
        k_w<<<2 * 2400, 256, 0, stream>>>(I, J, W, 0, SAMP);
        k_h<<<2 * 1000, 256, 0, stream>>>(W, SAMP);
        k_d<<<2 * 960,  256, 0, stream>>>(W + 5L * VOL, acc, 0, SAMP);
        k_fin<<<1, 64, 0, stream>>>(acc, out);
    } else {
        float* acc = (float*)((char*)d_ws + (size_t)SAMP * sizeof(__half));
        k_zero<<<1, 64, 0, stream>>>(acc);
        for (int s = 0; s < NS; ++s) {
            k_w<<<2400, 256, 0, stream>>>(I, J, W, s, 0);
            k_h<<<1000, 256, 0, stream>>>(W, 0);
            k_d<<<960,  256, 0, stream>>>(W + 5L * VOL, acc, s, 0);
        }
        k_fin<<<1, 64, 0, stream>>>(acc, out);
    }
}

// Round 4
// 119.726 us; speedup vs baseline: 1.5395x; 1.5395x over previous
//
#include <hip/hip_runtime.h>
#include <hip/hip_fp16.h>

#define D_ 160
#define H_ 192
#define W_ 160
#define PLANE (H_*W_)          // 30720
#define VOL (D_*PLANE)         // 4915200 per sample
#define NS 2
#define WSZ 729.0f

// B array per sample: 5 quantities (I, J, I*I, J*J, I*J), each VOL fp16,
// layout [q][d][h][w], holding the H,W-box-summed products.

// ---------------- zero accumulators ----------------
__global__ void k_zero(float* acc) {
    if (threadIdx.x < NS) acc[threadIdx.x] = 0.f;
}

// ---------------- pass 1: products + W-sum + H-sum -> fp16 B ----------------
// thread: 8 w (seg) x 8 h-outputs (chunk) x fixed d.
// Running H-sums rs[5][8] in fp32; entering/leaving rows recomputed from the
// fp32 inputs (recompute-subtract: bit-identical -> exact cancellation).
// per sample: seg(20) x chunk(24) x d(160) = 76800 threads = 300 blocks
__global__ __launch_bounds__(256) void k_wh(const float* __restrict__ I,
                                            const float* __restrict__ J,
                                            __half* __restrict__ B, long stride) {
    int b  = blockIdx.x;
    int sl = b / 300;
    int t  = (b % 300) * 256 + threadIdx.x;     // 0..76799
    int seg   = t % 20;
    int chunk = (t / 20) % 24;
    int d     = t / 480;                        // 0..159
    int w0 = seg * 8;
    int h0 = chunk * 8;
    const float* Ib = I + (long)sl * VOL + (long)d * PLANE;
    const float* Jb = J + (long)sl * VOL + (long)d * PLANE;
    __half* Bb = B + (long)sl * stride + (long)d * PLANE + w0;   // + q*VOL + h*W_

    float rs[5][8];
#pragma unroll
    for (int q = 0; q < 5; ++q)
#pragma unroll
        for (int k = 0; k < 8; ++k) rs[q][k] = 0.f;

    // one row's W-window sums for all 5 quantities, accumulated with +/- sign
    auto rowop = [&](int h, float sign) {
        if (h < 0 || h >= H_) return;
        const float* ri = Ib + (long)h * W_;
        const float* rj = Jb + (long)h * W_;
        float vI[16], vJ[16];
#pragma unroll
        for (int bq = 0; bq < 4; ++bq) {
            int f0 = w0 - 4 + 4 * bq;           // multiple of 4 -> aligned
            if (f0 >= 0 && f0 <= W_ - 4) {
                float4 a = *reinterpret_cast<const float4*>(ri + f0);
                float4 c = *reinterpret_cast<const float4*>(rj + f0);
                vI[4*bq+0]=a.x; vI[4*bq+1]=a.y; vI[4*bq+2]=a.z; vI[4*bq+3]=a.w;
                vJ[4*bq+0]=c.x; vJ[4*bq+1]=c.y; vJ[4*bq+2]=c.z; vJ[4*bq+3]=c.w;
            } else {
#pragma unroll
                for (int k = 0; k < 4; ++k) { vI[4*bq+k] = 0.f; vJ[4*bq+k] = 0.f; }
            }
        }
#pragma unroll
        for (int q = 0; q < 5; ++q) {
            float p[16];
#pragma unroll
            for (int i = 0; i < 16; ++i) {
                float a = vI[i], bb = vJ[i];
                p[i] = (q == 0) ? a : (q == 1) ? bb : (q == 2) ? a*a : (q == 3) ? bb*bb : a*bb;
            }
            float o[8];
            float ssum = 0.f;
#pragma unroll
            for (int i = 0; i < 9; ++i) ssum += p[i];
            o[0] = ssum;
#pragma unroll
            for (int k = 1; k < 8; ++k) { ssum += p[k + 8] - p[k - 1]; o[k] = ssum; }
#pragma unroll
            for (int k = 0; k < 8; ++k) rs[q][k] += sign * o[k];
        }
    };

    // init window rows [h0-4, h0+3]
    for (int i = 0; i < 8; ++i) rowop(h0 - 4 + i, 1.f);

    for (int hh = 0; hh < 8; ++hh) {
        int h = h0 + hh;
        rowop(h + 4, 1.f);                       // window now [h-4, h+4]
#pragma unroll
        for (int q = 0; q < 5; ++q) {
            union { __half hv[8]; int4 v; } u;
#pragma unroll
            for (int k = 0; k < 8; ++k) u.hv[k] = __float2half(rs[q][k]);
            *reinterpret_cast<int4*>(Bb + (long)q * VOL + (long)h * W_) = u.v;
        }
        rowop(h - 4, -1.f);                      // prep next: [h-3, h+4]
    }
}

// ---------------- pass 2: D-axis 9-box-sum + cc + reduction ----------------
// thread: 8 consecutive w (int4 fp16 loads), fixed h, d-chunk of 10.
// No ring: slide via add(d+5)/sub(d-4) re-loads (L2/L3 hits, exact cancel).
// per sample: wseg(20) x h(192) x chunk(16) = 61440 threads = 240 blocks
__global__ __launch_bounds__(256) void k_d(const __half* __restrict__ B,
                                           float* __restrict__ acc, long stride) {
    int b  = blockIdx.x;
    int sl = b / 240;
    int t  = (b % 240) * 256 + threadIdx.x;     // 0..61439
    int ws    = t % 20;
    int h     = (t / 20) % 192;
    int chunk = t / 3840;                       // 0..15
    int d0 = chunk * 10;
    const __half* Bb = B + (long)sl * stride + (long)h * W_ + ws * 8;  // + q*VOL + d*PLANE

    float s[5][8];
#pragma unroll
    for (int q = 0; q < 5; ++q)
#pragma unroll
        for (int k = 0; k < 8; ++k) s[q][k] = 0.f;

    // accumulate one d-plane row (8 fp16) into s[q][*] with sign
    auto plane = [&](int q, int d, float sign) {
        if (d < 0 || d >= D_) return;
        union { __half hv[8]; int4 v; } u;
        u.v = *reinterpret_cast<const int4*>(Bb + (long)q * VOL + (long)d * PLANE);
        if (q == 0) {
#pragma unroll
            for (int k = 0; k < 8; ++k) s[0][k] += sign * __half2float(u.hv[k]);
        } else if (q == 1) {
#pragma unroll
            for (int k = 0; k < 8; ++k) s[1][k] += sign * __half2float(u.hv[k]);
        } else if (q == 2) {
#pragma unroll
            for (int k = 0; k < 8; ++k) s[2][k] += sign * __half2float(u.hv[k]);
        } else if (q == 3) {
#pragma unroll
            for (int k = 0; k < 8; ++k) s[3][k] += sign * __half2float(u.hv[k]);
        } else {
#pragma unroll
            for (int k = 0; k < 8; ++k) s[4][k] += sign * __half2float(u.hv[k]);
        }
    };

    // init window [d0-4, d0+4]
#pragma unroll
    for (int q = 0; q < 5; ++q)
        for (int i = -4; i <= 4; ++i) plane(q, d0 + i, 1.f);

    float local = 0.f;
    for (int dd = 0; dd < 10; ++dd) {
#pragma unroll
        for (int k = 0; k < 8; ++k) {
            float Is = s[0][k], Js = s[1][k], I2 = s[2][k], J2 = s[3][k], IJ = s[4][k];
            float uI = Is * (1.f / WSZ), uJ = Js * (1.f / WSZ);
            float cross = IJ - uJ * Is - uI * Js + uI * uJ * WSZ;
            float Iv = I2 - 2.f * uI * Is + uI * uI * WSZ;
            float Jv = J2 - 2.f * uJ * Js + uJ * uJ * WSZ;
            local += 1.f - cross * cross / (Iv * Jv + 1e-5f);
        }
        int da = d0 + dd + 5, dsu = d0 + dd - 4;
#pragma unroll
        for (int q = 0; q < 5; ++q) { plane(q, da, 1.f); plane(q, dsu, -1.f); }
    }

    __shared__ float red[256];
    red[threadIdx.x] = local;
    __syncthreads();
    for (int off = 128; off > 0; off >>= 1) {
        if (threadIdx.x < off) red[threadIdx.x] += red[threadIdx.x + off];
        __syncthreads();
    }
    if (threadIdx.x == 0) atomicAdd(acc + sl, red[0]);
}

// ---------------- finalize ----------------
__global__ void k_fin(const float* __restrict__ acc, float* __restrict__ out) {
    if (threadIdx.x < NS) out[threadIdx.x] = acc[threadIdx.x] * (1.f / (float)VOL);
}

extern "C" void kernel_launch(void* const* d_in, const int* in_sizes, int n_in,
                              void* d_out, int out_size, void* d_ws, size_t ws_size,
                              hipStream_t stream) {
    const float* J = (const float*)d_in[0];   // y_pred
    const float* I = (const float*)d_in[1];   // y_true
    float* out = (float*)d_out;
    __half* B  = (__half*)d_ws;               // 2 samples x 5*VOL fp16 = 98.3 MB

    const long SAMP = 5L * VOL;               // B elements per sample
    float* acc = (float*)((char*)d_ws + (size_t)(NS * SAMP) * sizeof(__half));

    k_zero<<<1, 64, 0, stream>>>(acc);
    k_wh<<<NS * 300, 256, 0, stream>>>(I, J, B, SAMP);
    k_d<<<NS * 240, 256, 0, stream>>>(B, acc, SAMP);
    k_fin<<<1, 64, 0, stream>>>(acc, out);
}